// Round 5
// baseline (2108.273 us; speedup 1.0000x reference)
//
#include <hip/hip_runtime.h>
#include <cstddef>

// ---------------------------------------------------------------------------
// Decagon pipeline, fp32, algebraically collapsed output layers.
// Key identity: hardshrink(v, 1e-6) == v to within 1e-6, so
//   out2[t] = hshrink( xd[t] @ oW1 @ W2s + oB1 @ W2s + oB2s )
//           = hshrink( PP'[a] + QQ[b] ),  PP' = fX@M2_hi + Cvec folded in.
//
// R1: bucketed edge aggregation replacing 3.9M float atomicAdds. 765 -> 567.
// R2: split-K + LDS-staged W for latency-bound MLP; pq merged. 567 -> 509.
// R3: FAILED (+63): bucketed final broke write streaming. Reverted.
// R4: horizontal fusion, 13 graph nodes -> 7 (+memset). 572 -> 461.
//     Calibration: ~8-10 us per graph node (two independent diffs).
// R5: ONE persistent mega-kernel (768 blocks x 256 thr, launch_bounds(256,3)
//     => >=3 blocks/CU => all co-resident) with software grid barriers
//     (monotonic atomic counter + __threadfence release/acquire for
//     cross-XCD L2 visibility). Graph: 8 nodes -> 2 (memset + mega).
// ---------------------------------------------------------------------------

__device__ __forceinline__ float hshrink(float v) {
    return (fabsf(v) > 1e-6f) ? v : 0.0f;
}

// Grid-wide barrier: monotonic counter, device-scope. Requires all blocks
// co-resident (guaranteed: grid=768 <= 256 CU x 3 blocks/CU from
// __launch_bounds__(256,3)). Safety valve: bounded spin (~seconds) so a
// logic error fails visibly instead of hanging the harness.
__device__ __forceinline__ void gridbar(int* __restrict__ bar, int target) {
    __syncthreads();
    if (threadIdx.x == 0) {
        __threadfence();  // release: write-back this XCD's L2
        atomicAdd(bar, 1);
        int spins = 0;
        while (__hip_atomic_load(bar, __ATOMIC_ACQUIRE,
                                 __HIP_MEMORY_SCOPE_AGENT) < target) {
            __builtin_amdgcn_s_sleep(2);
            if (++spins > (1 << 26)) break;
        }
        __threadfence();  // acquire: invalidate stale L1/L2 lines
    }
    __syncthreads();
}

// ===========================================================================
// Persistent mega-kernel. Phases (grid barriers between):
//  P0: mlp1 split-K partials | edge degree count | outW2 column gather
//  P1: mlp2 (reduce partials + layer 2 + relu)   | 1024-wide scan
//  P2: edge bucket fill                          | M2 = [oW1;oB1] @ W2p
//  P3: aggsage (neighbor mean -> SAGE matmul), 2 drugs/block
//  P4: PPc = fX@M2_hi + cvec, QQc = fX@M2_lo
//  P5: out[t] = hshrink(PPc[a] + QQc[b]), streaming nt writes
// ===========================================================================
__global__ __launch_bounds__(256, 3) void k_mega(
    // P0 mlp1
    const float* __restrict__ dF, const float* __restrict__ W1,
    float* __restrict__ h1p, int nD, int F, int KS, int gx,
    // P0 deg
    const int* __restrict__ ei, int* __restrict__ deg, int E,
    // P0 w2g
    const float* __restrict__ oW2, const float* __restrict__ oB2,
    const int* __restrict__ sSes, float* __restrict__ W2p,
    float* __restrict__ B2p, int nSe, int S,
    // P1 mlp2 + scan
    const float* __restrict__ b1v, const float* __restrict__ W2,
    const float* __restrict__ b2v, float* __restrict__ xFd, int SK,
    int* __restrict__ off, int* __restrict__ cursor,
    // P2 fill + g16
    int* __restrict__ srcIdx, const float* __restrict__ oW1,
    const float* __restrict__ oB1, float* __restrict__ M2,
    // P3 aggsage
    const float* __restrict__ pE, const float* __restrict__ sWl,
    const float* __restrict__ sBl, const float* __restrict__ sWr,
    float* __restrict__ fX,
    // P4 pq
    float* __restrict__ PPc, float* __restrict__ QQc,
    // P5 final
    const int2* __restrict__ tpl2, float* __restrict__ out, int T,
    // barrier + virtual-block counts
    int* __restrict__ bar, int nbMlp, int nbDeg, int nbW2g, int nbMlp2,
    int nbFill, int nbG16) {
    __shared__ float sh[16 * 128 + 64 * 128];  // 40 KB, reused across phases
    const int tid = threadIdx.x;
    const int NB  = gridDim.x;

    // ---------------- P0: mlp1 | deg | w2g ----------------
    const int nv0 = nbMlp + nbDeg + nbW2g;
    for (int vb = blockIdx.x; vb < nv0; vb += NB) {
        if (vb < nbMlp) {
            float* As = sh;
            float* Ws = sh + 16 * 64;
            const int bx  = vb % gx;
            const int sk  = vb / gx;
            const int r0  = bx * 16;
            const int col = tid & 127;
            const int rh  = tid >> 7;
            float acc[8] = {};
            const int sr  = tid >> 4;
            const int sc4 = (tid & 15) * 4;
            const int ra  = min(r0 + sr, nD - 1);
            const int k0  = sk * KS;
            for (int kc = k0; kc < k0 + KS; kc += 64) {
                *(float4*)&As[sr * 64 + sc4] =
                    *(const float4*)(dF + (size_t)ra * F + kc + sc4);
#pragma unroll
                for (int l = 0; l < 8; l++) {
                    int idx = tid + l * 256;
                    int wr  = idx >> 5;
                    int wc  = (idx & 31) * 4;
                    *(float4*)&Ws[wr * 128 + wc] =
                        *(const float4*)(W1 + (size_t)(kc + wr) * 128 + wc);
                }
                __syncthreads();
                for (int k = 0; k < 64; k += 4) {
                    float w0 = Ws[(k + 0) * 128 + col];
                    float w1 = Ws[(k + 1) * 128 + col];
                    float w2 = Ws[(k + 2) * 128 + col];
                    float w3 = Ws[(k + 3) * 128 + col];
#pragma unroll
                    for (int r = 0; r < 8; r++) {
                        float4 av = *(const float4*)&As[(rh * 8 + r) * 64 + k];
                        acc[r] = fmaf(av.x, w0, acc[r]);
                        acc[r] = fmaf(av.y, w1, acc[r]);
                        acc[r] = fmaf(av.z, w2, acc[r]);
                        acc[r] = fmaf(av.w, w3, acc[r]);
                    }
                }
                __syncthreads();
            }
#pragma unroll
            for (int r = 0; r < 8; r++) {
                int row = r0 + rh * 8 + r;
                if (row < nD) h1p[((size_t)sk * nD + row) * 128 + col] = acc[r];
            }
        } else if (vb < nbMlp + nbDeg) {
            int e = (vb - nbMlp) * 256 + tid;
            if (e < E) {
                int dst = ei[E + e];
                if (dst < nD) atomicAdd(deg + dst, 1);
            }
        } else {
            int t = (vb - nbMlp - nbDeg) * 256 + tid;
            if (t < 128 * 512) {
                int k = t >> 9, j = t & 511;
                W2p[t] = (j < S) ? oW2[(size_t)k * nSe + sSes[j]] : 0.f;
            } else if (t < 128 * 512 + 512) {
                int j = t - 128 * 512;
                B2p[j] = (j < S) ? oB2[sSes[j]] : 0.f;
            }
        }
    }
    gridbar(bar, NB);

    // ---------------- P1: mlp2 | scan ----------------
    const int nv1 = nbMlp2 + 1;
    for (int vb = blockIdx.x; vb < nv1; vb += NB) {
        if (vb < nbMlp2) {
            float* As = sh;
            float* Ws = sh + 8 * 128;
            const int r0  = vb * 8;
            const int col = tid & 127;
            const int rh  = tid >> 7;
            const int sr  = tid >> 5;
            const int sc4 = (tid & 31) * 4;
            const int ra  = min(r0 + sr, nD - 1);
            float4 s = {0.f, 0.f, 0.f, 0.f};
            for (int sk = 0; sk < SK; sk++) {
                float4 v =
                    *(const float4*)(h1p + ((size_t)sk * nD + ra) * 128 + sc4);
                s.x += v.x; s.y += v.y; s.z += v.z; s.w += v.w;
            }
            float4 bb = *(const float4*)(b1v + sc4);
            s.x = fmaxf(s.x + bb.x, 0.f);
            s.y = fmaxf(s.y + bb.y, 0.f);
            s.z = fmaxf(s.z + bb.z, 0.f);
            s.w = fmaxf(s.w + bb.w, 0.f);
            *(float4*)&As[sr * 128 + sc4] = s;
            float acc[4] = {};
            for (int kc = 0; kc < 128; kc += 64) {
#pragma unroll
                for (int l = 0; l < 8; l++) {
                    int idx = tid + l * 256;
                    int wr  = idx >> 5;
                    int wc  = (idx & 31) * 4;
                    *(float4*)&Ws[wr * 128 + wc] =
                        *(const float4*)(W2 + (size_t)(kc + wr) * 128 + wc);
                }
                __syncthreads();
                for (int k = 0; k < 64; k += 4) {
                    float w0 = Ws[(k + 0) * 128 + col];
                    float w1 = Ws[(k + 1) * 128 + col];
                    float w2 = Ws[(k + 2) * 128 + col];
                    float w3 = Ws[(k + 3) * 128 + col];
#pragma unroll
                    for (int r = 0; r < 4; r++) {
                        float4 av =
                            *(const float4*)&As[(rh * 4 + r) * 128 + kc + k];
                        acc[r] = fmaf(av.x, w0, acc[r]);
                        acc[r] = fmaf(av.y, w1, acc[r]);
                        acc[r] = fmaf(av.z, w2, acc[r]);
                        acc[r] = fmaf(av.w, w3, acc[r]);
                    }
                }
                __syncthreads();
            }
            float b2s = b2v[col];
#pragma unroll
            for (int r = 0; r < 4; r++) {
                int row = r0 + rh * 4 + r;
                if (row < nD)
                    xFd[(size_t)row * 128 + col] = fmaxf(acc[r] + b2s, 0.f);
            }
        } else {
            // scan of deg[0..1024) (256 threads x int4)
            int* s = (int*)sh;
            int4 v = ((const int4*)deg)[tid];
            int loc = v.x + v.y + v.z + v.w;
            s[tid] = loc;
            __syncthreads();
            for (int o = 1; o < 256; o <<= 1) {
                int add = (tid >= o) ? s[tid - o] : 0;
                __syncthreads();
                s[tid] += add;
                __syncthreads();
            }
            int run = s[tid] - loc;
            int i0  = tid * 4;
            off[i0 + 0] = run; cursor[i0 + 0] = run; run += v.x;
            off[i0 + 1] = run; cursor[i0 + 1] = run; run += v.y;
            off[i0 + 2] = run; cursor[i0 + 2] = run; run += v.z;
            off[i0 + 3] = run; cursor[i0 + 3] = run; run += v.w;
            if (tid == 255) off[1024] = run;
            __syncthreads();
        }
    }
    gridbar(bar, 2 * NB);

    // ---------------- P2: fill | g16 ----------------
    const int nv2 = nbFill + nbG16;
    for (int vb = blockIdx.x; vb < nv2; vb += NB) {
        if (vb < nbFill) {
            int e = vb * 256 + tid;
            if (e < E) {
                int dst = ei[E + e];
                if (dst < nD) {
                    int pos = atomicAdd(cursor + dst, 1);
                    srcIdx[pos] = ei[e];
                }
            }
        } else {
            float* As = sh;
            const int gb = vb - nbFill;
            const int bx = gb % 17;
            const int cb = gb / 17;
            const int r0 = bx * 16;
            const int c4 = (tid & 31) * 4;
            const int rg = tid >> 5;
#pragma unroll
            for (int l = 0; l < 2; l++) {
                int idx = tid + l * 256;
                int row = idx >> 5, cc = (idx & 31) * 4;
                int ra  = min(r0 + row, 256);
                const float* ap = (ra < 256) ? (oW1 + (size_t)ra * 128) : oB1;
                *(float4*)&As[row * 128 + cc] = *(const float4*)(ap + cc);
            }
            __syncthreads();
            const float* Bp = W2p + cb * 128 + c4;
            float acc[2][4] = {};
            for (int k = 0; k < 128; k += 4) {
                float4 a0 = *(const float4*)&As[(rg * 2 + 0) * 128 + k];
                float4 a1 = *(const float4*)&As[(rg * 2 + 1) * 128 + k];
                const float* pa0 = &a0.x;
                const float* pa1 = &a1.x;
#pragma unroll
                for (int u = 0; u < 4; u++) {
                    float4 wv = *(const float4*)(Bp + (size_t)(k + u) * 512);
                    float v0 = pa0[u], v1 = pa1[u];
                    acc[0][0] = fmaf(v0, wv.x, acc[0][0]);
                    acc[0][1] = fmaf(v0, wv.y, acc[0][1]);
                    acc[0][2] = fmaf(v0, wv.z, acc[0][2]);
                    acc[0][3] = fmaf(v0, wv.w, acc[0][3]);
                    acc[1][0] = fmaf(v1, wv.x, acc[1][0]);
                    acc[1][1] = fmaf(v1, wv.y, acc[1][1]);
                    acc[1][2] = fmaf(v1, wv.z, acc[1][2]);
                    acc[1][3] = fmaf(v1, wv.w, acc[1][3]);
                }
            }
#pragma unroll
            for (int r = 0; r < 2; r++) {
                int row = r0 + rg * 2 + r;
                if (row < 257) {
                    float4 o = {acc[r][0], acc[r][1], acc[r][2], acc[r][3]};
                    *(float4*)(M2 + (size_t)row * 512 + cb * 128 + c4) = o;
                }
            }
            __syncthreads();  // LDS reuse guard for next virtual block
        }
    }
    gridbar(bar, 3 * NB);

    // ---------------- P3: aggsage (2 drugs/block) ----------------
    {
        float* ms = sh;        // [2][128]
        float* xs = sh + 256;  // [2][128]
        const int h = tid >> 7;
        const int c = tid & 127;
        const int nv3 = (nD + 1) / 2;
        for (int vb = blockIdx.x; vb < nv3; vb += NB) {
            int d = vb * 2 + h;
            float mv = 0.f, xv = 0.f;
            if (d < nD) {
                const int s0 = off[d], s1 = off[d + 1];
                float acc = 0.f;
                int j = s0;
                for (; j + 4 <= s1; j += 4) {
                    int i0 = srcIdx[j + 0];
                    int i1 = srcIdx[j + 1];
                    int i2 = srcIdx[j + 2];
                    int i3 = srcIdx[j + 3];
                    const float* p0 = (i0 < nD) ? (xFd + (size_t)i0 * 128)
                                                : (pE + (size_t)(i0 - nD) * 128);
                    const float* p1 = (i1 < nD) ? (xFd + (size_t)i1 * 128)
                                                : (pE + (size_t)(i1 - nD) * 128);
                    const float* p2 = (i2 < nD) ? (xFd + (size_t)i2 * 128)
                                                : (pE + (size_t)(i2 - nD) * 128);
                    const float* p3 = (i3 < nD) ? (xFd + (size_t)i3 * 128)
                                                : (pE + (size_t)(i3 - nD) * 128);
                    acc += p0[c]; acc += p1[c]; acc += p2[c]; acc += p3[c];
                }
                for (; j < s1; j++) {
                    int src = srcIdx[j];
                    const float* p = (src < nD)
                                         ? (xFd + (size_t)src * 128)
                                         : (pE + (size_t)(src - nD) * 128);
                    acc += p[c];
                }
                mv = acc / fmaxf((float)(s1 - s0), 1.0f);
                xv = xFd[(size_t)d * 128 + c];
            }
            ms[h * 128 + c] = mv;
            xs[h * 128 + c] = xv;
            __syncthreads();
            if (d < nD) {
                float a1 = 0.f, a2 = 0.f;
#pragma unroll 4
                for (int k = 0; k < 128; k++) {
                    a1 = fmaf(ms[h * 128 + k], sWl[(size_t)k * 128 + c], a1);
                    a2 = fmaf(xs[h * 128 + k], sWr[(size_t)k * 128 + c], a2);
                }
                fX[(size_t)d * 128 + c] = fmaxf(a1 + a2 + sBl[c], 0.f);
            }
            __syncthreads();  // LDS reuse guard
        }
    }
    gridbar(bar, 4 * NB);

    // ---------------- P4: pq ----------------
    {
        float* As = sh;
        float* Bs = sh + 16 * 128;
        const int gx2 = (nD + 15) / 16;
        const int nv4 = gx2 * 8;
        const int c4 = (tid & 31) * 4;
        const int rg = tid >> 5;
        for (int vb = blockIdx.x; vb < nv4; vb += NB) {
            const int bx = vb % gx2;
            const int cb = vb / gx2;  // 0..7
            const int r0 = bx * 16;
            const float* B = M2 + (size_t)(cb >> 2) * (128 * 512) + (cb & 3) * 128;
#pragma unroll
            for (int l = 0; l < 2; l++) {
                int idx = tid + l * 256;
                int row = idx >> 5, cc = (idx & 31) * 4;
                int ra  = min(r0 + row, nD - 1);
                *(float4*)&As[row * 128 + cc] =
                    *(const float4*)(fX + (size_t)ra * 128 + cc);
            }
            float acc[2][4] = {};
            for (int kc = 0; kc < 128; kc += 64) {
#pragma unroll
                for (int l = 0; l < 8; l++) {
                    int idx = tid + l * 256;
                    int wr  = idx >> 5;
                    int wc  = (idx & 31) * 4;
                    *(float4*)&Bs[wr * 128 + wc] =
                        *(const float4*)(B + (size_t)(kc + wr) * 512 + wc);
                }
                __syncthreads();
                for (int k = 0; k < 64; k += 4) {
                    float4 a0 = *(const float4*)&As[(rg * 2 + 0) * 128 + kc + k];
                    float4 a1 = *(const float4*)&As[(rg * 2 + 1) * 128 + kc + k];
                    const float* pa0 = &a0.x;
                    const float* pa1 = &a1.x;
#pragma unroll
                    for (int u = 0; u < 4; u++) {
                        float4 wv = *(const float4*)&Bs[(k + u) * 128 + c4];
                        float v0 = pa0[u], v1 = pa1[u];
                        acc[0][0] = fmaf(v0, wv.x, acc[0][0]);
                        acc[0][1] = fmaf(v0, wv.y, acc[0][1]);
                        acc[0][2] = fmaf(v0, wv.z, acc[0][2]);
                        acc[0][3] = fmaf(v0, wv.w, acc[0][3]);
                        acc[1][0] = fmaf(v1, wv.x, acc[1][0]);
                        acc[1][1] = fmaf(v1, wv.y, acc[1][1]);
                        acc[1][2] = fmaf(v1, wv.z, acc[1][2]);
                        acc[1][3] = fmaf(v1, wv.w, acc[1][3]);
                    }
                }
                __syncthreads();
            }
            float4 cv = {0.f, 0.f, 0.f, 0.f};
            int colb = (cb & 3) * 128 + c4;
            if (cb < 4) {
                float4 m  = *(const float4*)(M2 + (size_t)256 * 512 + colb);
                float4 b2 = *(const float4*)(B2p + colb);
                cv.x = m.x + b2.x; cv.y = m.y + b2.y;
                cv.z = m.z + b2.z; cv.w = m.w + b2.w;
            }
            float* dst = (cb < 4) ? PPc : QQc;
#pragma unroll
            for (int r = 0; r < 2; r++) {
                int row = r0 + rg * 2 + r;
                if (row < nD) {
                    float4 o = {acc[r][0] + cv.x, acc[r][1] + cv.y,
                                acc[r][2] + cv.z, acc[r][3] + cv.w};
                    *(float4*)(dst + (size_t)row * 512 + colb) = o;
                }
            }
        }
    }
    gridbar(bar, 5 * NB);

    // ---------------- P5: final streaming epilogue ----------------
    {
        const int h = tid >> 7;
        const int i = tid & 127;
        const int nv5 = (T + 1) / 2;
        const bool act = (i < (S >> 2));
        for (int vb = blockIdx.x; vb < nv5; vb += NB) {
            int t = vb * 2 + h;
            if (t < T && act) {
                int2 ab = tpl2[t];
                float4 p = ((const float4*)(PPc + (size_t)ab.x * 512))[i];
                float4 q = ((const float4*)(QQc + (size_t)ab.y * 512))[i];
                float o0 = hshrink(p.x + q.x);
                float o1 = hshrink(p.y + q.y);
                float o2 = hshrink(p.z + q.z);
                float o3 = hshrink(p.w + q.w);
                float* po = out + (size_t)t * S + i * 4;
                __builtin_nontemporal_store(o0, po + 0);
                __builtin_nontemporal_store(o1, po + 1);
                __builtin_nontemporal_store(o2, po + 2);
                __builtin_nontemporal_store(o3, po + 3);
            }
        }
    }
}

extern "C" void kernel_launch(void* const* d_in, const int* in_sizes, int n_in,
                              void* d_out, int out_size, void* d_ws, size_t ws_size,
                              hipStream_t stream) {
    const float* dF   = (const float*)d_in[0];
    const int*   ei   = (const int*)d_in[1];
    const int*   tpl  = (const int*)d_in[2];
    const int*   sSes = (const int*)d_in[3];
    const float* W1   = (const float*)d_in[4];
    const float* b1   = (const float*)d_in[5];
    const float* W2   = (const float*)d_in[6];
    const float* b2   = (const float*)d_in[7];
    const float* pE   = (const float*)d_in[8];
    const float* sWl  = (const float*)d_in[9];
    const float* sBl  = (const float*)d_in[10];
    const float* sWr  = (const float*)d_in[11];
    const float* oW1  = (const float*)d_in[12];
    const float* oB1  = (const float*)d_in[13];
    const float* oW2  = (const float*)d_in[14];
    const float* oB2  = (const float*)d_in[15];

    const int D    = 128;
    const int F    = in_sizes[4] / D;   // 2048
    const int nD   = in_sizes[0] / F;   // 1000
    const int E    = in_sizes[1] / 2;   // 640000
    const int T    = in_sizes[2] / 2;   // 150000
    const int S    = in_sizes[3];       // 500
    const int nSe  = in_sizes[15];      // 964
    const int SK   = 4;                 // split-K for layer-1 MLP

    float* ws   = (float*)d_ws;
    float* xFd  = ws;                                // nD*128
    float* h1p  = xFd + (size_t)nD * D;              // SK*nD*128
    float* fX   = h1p + (size_t)SK * nD * D;         // nD*128
    float* W2p  = fX + (size_t)nD * D;               // 128*512
    float* B2p  = W2p + 128 * 512;                   // 512
    float* M2   = B2p + 512;                         // 257*512
    float* PPc  = M2 + 257 * 512;                    // nD*512 (2 MB)
    float* QQc  = PPc + (size_t)nD * 512;            // nD*512 (2 MB)
    int* deg    = (int*)(QQc + (size_t)nD * 512);    // 1024 (16B-aligned)
    int* bar    = deg + 1024;                        // 16 (zeroed with deg)
    int* off    = bar + 16;                          // 1025
    int* cursor = off + 1025;                        // 1024
    int* srcIdx = cursor + 1024 + 3;                 // <= E

    const int gx     = (nD + 15) / 16;                 // 63
    const int nbMlp  = gx * SK;                        // 252
    const int nbDeg  = (E + 255) / 256;                // 2500
    const int nbW2g  = (128 * 512 + 512 + 255) / 256;  // 258
    const int nbMlp2 = (nD + 7) / 8;                   // 125
    const int nbFill = (E + 255) / 256;                // 2500
    const int nbG16  = 17 * 4;                         // 68

    // zero deg + barrier counter (adjacent, one memset)
    hipMemsetAsync(deg, 0, (1024 + 16) * sizeof(int), stream);
    // single persistent mega-kernel: 768 blocks co-resident (256,3)
    k_mega<<<768, 256, 0, stream>>>(
        dF, W1, h1p, nD, F, F / SK, gx,
        ei, deg, E,
        oW2, oB2, sSes, W2p, B2p, nSe, S,
        b1, W2, b2, xFd, SK, off, cursor,
        srcIdx, oW1, oB1, M2,
        pE, sWl, sBl, sWr, fX,
        PPc, QQc,
        (const int2*)tpl, (float*)d_out, T,
        bar, nbMlp, nbDeg, nbW2g, nbMlp2, nbFill, nbG16);
}

// Round 6
// 1097.092 us; speedup vs baseline: 1.9217x; 1.9217x over previous
//
#include <hip/hip_runtime.h>
#include <cstddef>

// ---------------------------------------------------------------------------
// Decagon pipeline, fp32, algebraically collapsed output layers.
// Key identity: hardshrink(v, 1e-6) == v to within 1e-6, so
//   out2[t] = hshrink( xd[t] @ oW1 @ W2s + oB1 @ W2s + oB2s )
//           = hshrink( PP'[a] + QQ[b] ),  PP' = fX@M2_hi + Cvec folded in.
//
// R1: bucketed edge aggregation replacing 3.9M float atomicAdds. 765 -> 567.
// R2: split-K + LDS-staged W for latency-bound MLP; pq merged. 567 -> 509.
// R3: FAILED (+63): bucketed final broke write streaming. Reverted.
// R4: horizontal fusion, 13 graph nodes -> 7 (+memset). 572 -> 461.
// R5: FAILED (2108): mega-kernel barrier polled with ACQUIRE ordering; on
//     gfx94x+ every agent-scope acquire load emits buffer_inv (L2
//     invalidate) -> 768 spinners thrashed all 8 XCD L2s (FETCH 382 MB,
//     WRITE 701 MB of phantom traffic, 7% HBM, VALUBusy 1.5%).
// R6: poll with RELAXED (cache-bypassing load, no invalidate); single
//     release fence before arrive, single acquire fence after the loop.
//     Everything else identical to R5.
// ---------------------------------------------------------------------------

__device__ __forceinline__ float hshrink(float v) {
    return (fabsf(v) > 1e-6f) ? v : 0.0f;
}

// Grid-wide barrier: monotonic counter, device-scope. All blocks co-resident
// (grid=768 <= 256 CU x 3 blocks/CU from __launch_bounds__(256,3)).
// CRITICAL (R5 lesson): the poll must be RELAXED — an ACQUIRE poll emits a
// full L2 invalidate per iteration on gfx94x+. One release fence before the
// arrive, one acquire fence after the condition is met.
__device__ __forceinline__ void gridbar(int* __restrict__ bar, int target) {
    __syncthreads();
    if (threadIdx.x == 0) {
        __threadfence();  // release: write back this XCD's dirty L2 once
        atomicAdd(bar, 1);
        int spins = 0;
        while (__hip_atomic_load(bar, __ATOMIC_RELAXED,
                                 __HIP_MEMORY_SCOPE_AGENT) < target) {
            __builtin_amdgcn_s_sleep(4);
            if (++spins > (1 << 26)) break;  // fail visibly, not a hang
        }
        __threadfence();  // acquire: invalidate stale lines once
    }
    __syncthreads();
}

// ===========================================================================
// Persistent mega-kernel. Phases (grid barriers between):
//  P0: mlp1 split-K partials | edge degree count | outW2 column gather
//  P1: mlp2 (reduce partials + layer 2 + relu)   | 1024-wide scan
//  P2: edge bucket fill                          | M2 = [oW1;oB1] @ W2p
//  P3: aggsage (neighbor mean -> SAGE matmul), 2 drugs/block
//  P4: PPc = fX@M2_hi + cvec, QQc = fX@M2_lo
//  P5: out[t] = hshrink(PPc[a] + QQc[b]), streaming nt writes
// ===========================================================================
__global__ __launch_bounds__(256, 3) void k_mega(
    // P0 mlp1
    const float* __restrict__ dF, const float* __restrict__ W1,
    float* __restrict__ h1p, int nD, int F, int KS, int gx,
    // P0 deg
    const int* __restrict__ ei, int* __restrict__ deg, int E,
    // P0 w2g
    const float* __restrict__ oW2, const float* __restrict__ oB2,
    const int* __restrict__ sSes, float* __restrict__ W2p,
    float* __restrict__ B2p, int nSe, int S,
    // P1 mlp2 + scan
    const float* __restrict__ b1v, const float* __restrict__ W2,
    const float* __restrict__ b2v, float* __restrict__ xFd, int SK,
    int* __restrict__ off, int* __restrict__ cursor,
    // P2 fill + g16
    int* __restrict__ srcIdx, const float* __restrict__ oW1,
    const float* __restrict__ oB1, float* __restrict__ M2,
    // P3 aggsage
    const float* __restrict__ pE, const float* __restrict__ sWl,
    const float* __restrict__ sBl, const float* __restrict__ sWr,
    float* __restrict__ fX,
    // P4 pq
    float* __restrict__ PPc, float* __restrict__ QQc,
    // P5 final
    const int2* __restrict__ tpl2, float* __restrict__ out, int T,
    // barrier + virtual-block counts
    int* __restrict__ bar, int nbMlp, int nbDeg, int nbW2g, int nbMlp2,
    int nbFill, int nbG16) {
    __shared__ float sh[16 * 128 + 64 * 128];  // 40 KB, reused across phases
    const int tid = threadIdx.x;
    const int NB  = gridDim.x;

    // ---------------- P0: mlp1 | deg | w2g ----------------
    const int nv0 = nbMlp + nbDeg + nbW2g;
    for (int vb = blockIdx.x; vb < nv0; vb += NB) {
        if (vb < nbMlp) {
            float* As = sh;
            float* Ws = sh + 16 * 64;
            const int bx  = vb % gx;
            const int sk  = vb / gx;
            const int r0  = bx * 16;
            const int col = tid & 127;
            const int rh  = tid >> 7;
            float acc[8] = {};
            const int sr  = tid >> 4;
            const int sc4 = (tid & 15) * 4;
            const int ra  = min(r0 + sr, nD - 1);
            const int k0  = sk * KS;
            for (int kc = k0; kc < k0 + KS; kc += 64) {
                *(float4*)&As[sr * 64 + sc4] =
                    *(const float4*)(dF + (size_t)ra * F + kc + sc4);
#pragma unroll
                for (int l = 0; l < 8; l++) {
                    int idx = tid + l * 256;
                    int wr  = idx >> 5;
                    int wc  = (idx & 31) * 4;
                    *(float4*)&Ws[wr * 128 + wc] =
                        *(const float4*)(W1 + (size_t)(kc + wr) * 128 + wc);
                }
                __syncthreads();
                for (int k = 0; k < 64; k += 4) {
                    float w0 = Ws[(k + 0) * 128 + col];
                    float w1 = Ws[(k + 1) * 128 + col];
                    float w2 = Ws[(k + 2) * 128 + col];
                    float w3 = Ws[(k + 3) * 128 + col];
#pragma unroll
                    for (int r = 0; r < 8; r++) {
                        float4 av = *(const float4*)&As[(rh * 8 + r) * 64 + k];
                        acc[r] = fmaf(av.x, w0, acc[r]);
                        acc[r] = fmaf(av.y, w1, acc[r]);
                        acc[r] = fmaf(av.z, w2, acc[r]);
                        acc[r] = fmaf(av.w, w3, acc[r]);
                    }
                }
                __syncthreads();
            }
#pragma unroll
            for (int r = 0; r < 8; r++) {
                int row = r0 + rh * 8 + r;
                if (row < nD) h1p[((size_t)sk * nD + row) * 128 + col] = acc[r];
            }
        } else if (vb < nbMlp + nbDeg) {
            int e = (vb - nbMlp) * 256 + tid;
            if (e < E) {
                int dst = ei[E + e];
                if (dst < nD) atomicAdd(deg + dst, 1);
            }
        } else {
            int t = (vb - nbMlp - nbDeg) * 256 + tid;
            if (t < 128 * 512) {
                int k = t >> 9, j = t & 511;
                W2p[t] = (j < S) ? oW2[(size_t)k * nSe + sSes[j]] : 0.f;
            } else if (t < 128 * 512 + 512) {
                int j = t - 128 * 512;
                B2p[j] = (j < S) ? oB2[sSes[j]] : 0.f;
            }
        }
    }
    gridbar(bar, NB);

    // ---------------- P1: mlp2 | scan ----------------
    const int nv1 = nbMlp2 + 1;
    for (int vb = blockIdx.x; vb < nv1; vb += NB) {
        if (vb < nbMlp2) {
            float* As = sh;
            float* Ws = sh + 8 * 128;
            const int r0  = vb * 8;
            const int col = tid & 127;
            const int rh  = tid >> 7;
            const int sr  = tid >> 5;
            const int sc4 = (tid & 31) * 4;
            const int ra  = min(r0 + sr, nD - 1);
            float4 s = {0.f, 0.f, 0.f, 0.f};
            for (int sk = 0; sk < SK; sk++) {
                float4 v =
                    *(const float4*)(h1p + ((size_t)sk * nD + ra) * 128 + sc4);
                s.x += v.x; s.y += v.y; s.z += v.z; s.w += v.w;
            }
            float4 bb = *(const float4*)(b1v + sc4);
            s.x = fmaxf(s.x + bb.x, 0.f);
            s.y = fmaxf(s.y + bb.y, 0.f);
            s.z = fmaxf(s.z + bb.z, 0.f);
            s.w = fmaxf(s.w + bb.w, 0.f);
            *(float4*)&As[sr * 128 + sc4] = s;
            float acc[4] = {};
            for (int kc = 0; kc < 128; kc += 64) {
#pragma unroll
                for (int l = 0; l < 8; l++) {
                    int idx = tid + l * 256;
                    int wr  = idx >> 5;
                    int wc  = (idx & 31) * 4;
                    *(float4*)&Ws[wr * 128 + wc] =
                        *(const float4*)(W2 + (size_t)(kc + wr) * 128 + wc);
                }
                __syncthreads();
                for (int k = 0; k < 64; k += 4) {
                    float w0 = Ws[(k + 0) * 128 + col];
                    float w1 = Ws[(k + 1) * 128 + col];
                    float w2 = Ws[(k + 2) * 128 + col];
                    float w3 = Ws[(k + 3) * 128 + col];
#pragma unroll
                    for (int r = 0; r < 4; r++) {
                        float4 av =
                            *(const float4*)&As[(rh * 4 + r) * 128 + kc + k];
                        acc[r] = fmaf(av.x, w0, acc[r]);
                        acc[r] = fmaf(av.y, w1, acc[r]);
                        acc[r] = fmaf(av.z, w2, acc[r]);
                        acc[r] = fmaf(av.w, w3, acc[r]);
                    }
                }
                __syncthreads();
            }
            float b2s = b2v[col];
#pragma unroll
            for (int r = 0; r < 4; r++) {
                int row = r0 + rh * 4 + r;
                if (row < nD)
                    xFd[(size_t)row * 128 + col] = fmaxf(acc[r] + b2s, 0.f);
            }
        } else {
            // scan of deg[0..1024) (256 threads x int4)
            int* s = (int*)sh;
            int4 v = ((const int4*)deg)[tid];
            int loc = v.x + v.y + v.z + v.w;
            s[tid] = loc;
            __syncthreads();
            for (int o = 1; o < 256; o <<= 1) {
                int add = (tid >= o) ? s[tid - o] : 0;
                __syncthreads();
                s[tid] += add;
                __syncthreads();
            }
            int run = s[tid] - loc;
            int i0  = tid * 4;
            off[i0 + 0] = run; cursor[i0 + 0] = run; run += v.x;
            off[i0 + 1] = run; cursor[i0 + 1] = run; run += v.y;
            off[i0 + 2] = run; cursor[i0 + 2] = run; run += v.z;
            off[i0 + 3] = run; cursor[i0 + 3] = run; run += v.w;
            if (tid == 255) off[1024] = run;
            __syncthreads();
        }
    }
    gridbar(bar, 2 * NB);

    // ---------------- P2: fill | g16 ----------------
    const int nv2 = nbFill + nbG16;
    for (int vb = blockIdx.x; vb < nv2; vb += NB) {
        if (vb < nbFill) {
            int e = vb * 256 + tid;
            if (e < E) {
                int dst = ei[E + e];
                if (dst < nD) {
                    int pos = atomicAdd(cursor + dst, 1);
                    srcIdx[pos] = ei[e];
                }
            }
        } else {
            float* As = sh;
            const int gb = vb - nbFill;
            const int bx = gb % 17;
            const int cb = gb / 17;
            const int r0 = bx * 16;
            const int c4 = (tid & 31) * 4;
            const int rg = tid >> 5;
#pragma unroll
            for (int l = 0; l < 2; l++) {
                int idx = tid + l * 256;
                int row = idx >> 5, cc = (idx & 31) * 4;
                int ra  = min(r0 + row, 256);
                const float* ap = (ra < 256) ? (oW1 + (size_t)ra * 128) : oB1;
                *(float4*)&As[row * 128 + cc] = *(const float4*)(ap + cc);
            }
            __syncthreads();
            const float* Bp = W2p + cb * 128 + c4;
            float acc[2][4] = {};
            for (int k = 0; k < 128; k += 4) {
                float4 a0 = *(const float4*)&As[(rg * 2 + 0) * 128 + k];
                float4 a1 = *(const float4*)&As[(rg * 2 + 1) * 128 + k];
                const float* pa0 = &a0.x;
                const float* pa1 = &a1.x;
#pragma unroll
                for (int u = 0; u < 4; u++) {
                    float4 wv = *(const float4*)(Bp + (size_t)(k + u) * 512);
                    float v0 = pa0[u], v1 = pa1[u];
                    acc[0][0] = fmaf(v0, wv.x, acc[0][0]);
                    acc[0][1] = fmaf(v0, wv.y, acc[0][1]);
                    acc[0][2] = fmaf(v0, wv.z, acc[0][2]);
                    acc[0][3] = fmaf(v0, wv.w, acc[0][3]);
                    acc[1][0] = fmaf(v1, wv.x, acc[1][0]);
                    acc[1][1] = fmaf(v1, wv.y, acc[1][1]);
                    acc[1][2] = fmaf(v1, wv.z, acc[1][2]);
                    acc[1][3] = fmaf(v1, wv.w, acc[1][3]);
                }
            }
#pragma unroll
            for (int r = 0; r < 2; r++) {
                int row = r0 + rg * 2 + r;
                if (row < 257) {
                    float4 o = {acc[r][0], acc[r][1], acc[r][2], acc[r][3]};
                    *(float4*)(M2 + (size_t)row * 512 + cb * 128 + c4) = o;
                }
            }
            __syncthreads();  // LDS reuse guard for next virtual block
        }
    }
    gridbar(bar, 3 * NB);

    // ---------------- P3: aggsage (2 drugs/block) ----------------
    {
        float* ms = sh;        // [2][128]
        float* xs = sh + 256;  // [2][128]
        const int h = tid >> 7;
        const int c = tid & 127;
        const int nv3 = (nD + 1) / 2;
        for (int vb = blockIdx.x; vb < nv3; vb += NB) {
            int d = vb * 2 + h;
            float mv = 0.f, xv = 0.f;
            if (d < nD) {
                const int s0 = off[d], s1 = off[d + 1];
                float acc = 0.f;
                int j = s0;
                for (; j + 4 <= s1; j += 4) {
                    int i0 = srcIdx[j + 0];
                    int i1 = srcIdx[j + 1];
                    int i2 = srcIdx[j + 2];
                    int i3 = srcIdx[j + 3];
                    const float* p0 = (i0 < nD) ? (xFd + (size_t)i0 * 128)
                                                : (pE + (size_t)(i0 - nD) * 128);
                    const float* p1 = (i1 < nD) ? (xFd + (size_t)i1 * 128)
                                                : (pE + (size_t)(i1 - nD) * 128);
                    const float* p2 = (i2 < nD) ? (xFd + (size_t)i2 * 128)
                                                : (pE + (size_t)(i2 - nD) * 128);
                    const float* p3 = (i3 < nD) ? (xFd + (size_t)i3 * 128)
                                                : (pE + (size_t)(i3 - nD) * 128);
                    acc += p0[c]; acc += p1[c]; acc += p2[c]; acc += p3[c];
                }
                for (; j < s1; j++) {
                    int src = srcIdx[j];
                    const float* p = (src < nD)
                                         ? (xFd + (size_t)src * 128)
                                         : (pE + (size_t)(src - nD) * 128);
                    acc += p[c];
                }
                mv = acc / fmaxf((float)(s1 - s0), 1.0f);
                xv = xFd[(size_t)d * 128 + c];
            }
            ms[h * 128 + c] = mv;
            xs[h * 128 + c] = xv;
            __syncthreads();
            if (d < nD) {
                float a1 = 0.f, a2 = 0.f;
#pragma unroll 4
                for (int k = 0; k < 128; k++) {
                    a1 = fmaf(ms[h * 128 + k], sWl[(size_t)k * 128 + c], a1);
                    a2 = fmaf(xs[h * 128 + k], sWr[(size_t)k * 128 + c], a2);
                }
                fX[(size_t)d * 128 + c] = fmaxf(a1 + a2 + sBl[c], 0.f);
            }
            __syncthreads();  // LDS reuse guard
        }
    }
    gridbar(bar, 4 * NB);

    // ---------------- P4: pq ----------------
    {
        float* As = sh;
        float* Bs = sh + 16 * 128;
        const int gx2 = (nD + 15) / 16;
        const int nv4 = gx2 * 8;
        const int c4 = (tid & 31) * 4;
        const int rg = tid >> 5;
        for (int vb = blockIdx.x; vb < nv4; vb += NB) {
            const int bx = vb % gx2;
            const int cb = vb / gx2;  // 0..7
            const int r0 = bx * 16;
            const float* B = M2 + (size_t)(cb >> 2) * (128 * 512) + (cb & 3) * 128;
#pragma unroll
            for (int l = 0; l < 2; l++) {
                int idx = tid + l * 256;
                int row = idx >> 5, cc = (idx & 31) * 4;
                int ra  = min(r0 + row, nD - 1);
                *(float4*)&As[row * 128 + cc] =
                    *(const float4*)(fX + (size_t)ra * 128 + cc);
            }
            float acc[2][4] = {};
            for (int kc = 0; kc < 128; kc += 64) {
#pragma unroll
                for (int l = 0; l < 8; l++) {
                    int idx = tid + l * 256;
                    int wr  = idx >> 5;
                    int wc  = (idx & 31) * 4;
                    *(float4*)&Bs[wr * 128 + wc] =
                        *(const float4*)(B + (size_t)(kc + wr) * 512 + wc);
                }
                __syncthreads();
                for (int k = 0; k < 64; k += 4) {
                    float4 a0 = *(const float4*)&As[(rg * 2 + 0) * 128 + kc + k];
                    float4 a1 = *(const float4*)&As[(rg * 2 + 1) * 128 + kc + k];
                    const float* pa0 = &a0.x;
                    const float* pa1 = &a1.x;
#pragma unroll
                    for (int u = 0; u < 4; u++) {
                        float4 wv = *(const float4*)&Bs[(k + u) * 128 + c4];
                        float v0 = pa0[u], v1 = pa1[u];
                        acc[0][0] = fmaf(v0, wv.x, acc[0][0]);
                        acc[0][1] = fmaf(v0, wv.y, acc[0][1]);
                        acc[0][2] = fmaf(v0, wv.z, acc[0][2]);
                        acc[0][3] = fmaf(v0, wv.w, acc[0][3]);
                        acc[1][0] = fmaf(v1, wv.x, acc[1][0]);
                        acc[1][1] = fmaf(v1, wv.y, acc[1][1]);
                        acc[1][2] = fmaf(v1, wv.z, acc[1][2]);
                        acc[1][3] = fmaf(v1, wv.w, acc[1][3]);
                    }
                }
                __syncthreads();
            }
            float4 cv = {0.f, 0.f, 0.f, 0.f};
            int colb = (cb & 3) * 128 + c4;
            if (cb < 4) {
                float4 m  = *(const float4*)(M2 + (size_t)256 * 512 + colb);
                float4 b2 = *(const float4*)(B2p + colb);
                cv.x = m.x + b2.x; cv.y = m.y + b2.y;
                cv.z = m.z + b2.z; cv.w = m.w + b2.w;
            }
            float* dst = (cb < 4) ? PPc : QQc;
#pragma unroll
            for (int r = 0; r < 2; r++) {
                int row = r0 + rg * 2 + r;
                if (row < nD) {
                    float4 o = {acc[r][0] + cv.x, acc[r][1] + cv.y,
                                acc[r][2] + cv.z, acc[r][3] + cv.w};
                    *(float4*)(dst + (size_t)row * 512 + colb) = o;
                }
            }
        }
    }
    gridbar(bar, 5 * NB);

    // ---------------- P5: final streaming epilogue ----------------
    {
        const int h = tid >> 7;
        const int i = tid & 127;
        const int nv5 = (T + 1) / 2;
        const bool act = (i < (S >> 2));
        for (int vb = blockIdx.x; vb < nv5; vb += NB) {
            int t = vb * 2 + h;
            if (t < T && act) {
                int2 ab = tpl2[t];
                float4 p = ((const float4*)(PPc + (size_t)ab.x * 512))[i];
                float4 q = ((const float4*)(QQc + (size_t)ab.y * 512))[i];
                float o0 = hshrink(p.x + q.x);
                float o1 = hshrink(p.y + q.y);
                float o2 = hshrink(p.z + q.z);
                float o3 = hshrink(p.w + q.w);
                float* po = out + (size_t)t * S + i * 4;
                __builtin_nontemporal_store(o0, po + 0);
                __builtin_nontemporal_store(o1, po + 1);
                __builtin_nontemporal_store(o2, po + 2);
                __builtin_nontemporal_store(o3, po + 3);
            }
        }
    }
}

extern "C" void kernel_launch(void* const* d_in, const int* in_sizes, int n_in,
                              void* d_out, int out_size, void* d_ws, size_t ws_size,
                              hipStream_t stream) {
    const float* dF   = (const float*)d_in[0];
    const int*   ei   = (const int*)d_in[1];
    const int*   tpl  = (const int*)d_in[2];
    const int*   sSes = (const int*)d_in[3];
    const float* W1   = (const float*)d_in[4];
    const float* b1   = (const float*)d_in[5];
    const float* W2   = (const float*)d_in[6];
    const float* b2   = (const float*)d_in[7];
    const float* pE   = (const float*)d_in[8];
    const float* sWl  = (const float*)d_in[9];
    const float* sBl  = (const float*)d_in[10];
    const float* sWr  = (const float*)d_in[11];
    const float* oW1  = (const float*)d_in[12];
    const float* oB1  = (const float*)d_in[13];
    const float* oW2  = (const float*)d_in[14];
    const float* oB2  = (const float*)d_in[15];

    const int D    = 128;
    const int F    = in_sizes[4] / D;   // 2048
    const int nD   = in_sizes[0] / F;   // 1000
    const int E    = in_sizes[1] / 2;   // 640000
    const int T    = in_sizes[2] / 2;   // 150000
    const int S    = in_sizes[3];       // 500
    const int nSe  = in_sizes[15];      // 964
    const int SK   = 4;                 // split-K for layer-1 MLP

    float* ws   = (float*)d_ws;
    float* xFd  = ws;                                // nD*128
    float* h1p  = xFd + (size_t)nD * D;              // SK*nD*128
    float* fX   = h1p + (size_t)SK * nD * D;         // nD*128
    float* W2p  = fX + (size_t)nD * D;               // 128*512
    float* B2p  = W2p + 128 * 512;                   // 512
    float* M2   = B2p + 512;                         // 257*512
    float* PPc  = M2 + 257 * 512;                    // nD*512 (2 MB)
    float* QQc  = PPc + (size_t)nD * 512;            // nD*512 (2 MB)
    int* deg    = (int*)(QQc + (size_t)nD * 512);    // 1024 (16B-aligned)
    int* bar    = deg + 1024;                        // 16 (zeroed with deg)
    int* off    = bar + 16;                          // 1025
    int* cursor = off + 1025;                        // 1024
    int* srcIdx = cursor + 1024 + 3;                 // <= E

    const int gx     = (nD + 15) / 16;                 // 63
    const int nbMlp  = gx * SK;                        // 252
    const int nbDeg  = (E + 255) / 256;                // 2500
    const int nbW2g  = (128 * 512 + 512 + 255) / 256;  // 258
    const int nbMlp2 = (nD + 7) / 8;                   // 125
    const int nbFill = (E + 255) / 256;                // 2500
    const int nbG16  = 17 * 4;                         // 68

    // zero deg + barrier counter (adjacent, one memset)
    hipMemsetAsync(deg, 0, (1024 + 16) * sizeof(int), stream);
    // single persistent mega-kernel: 768 blocks co-resident (256,3)
    k_mega<<<768, 256, 0, stream>>>(
        dF, W1, h1p, nD, F, F / SK, gx,
        ei, deg, E,
        oW2, oB2, sSes, W2p, B2p, nSe, S,
        b1, W2, b2, xFd, SK, off, cursor,
        srcIdx, oW1, oB1, M2,
        pE, sWl, sBl, sWr, fX,
        PPc, QQc,
        (const int2*)tpl, (float*)d_out, T,
        bar, nbMlp, nbDeg, nbW2g, nbMlp2, nbFill, nbG16);
}